// Round 15
// baseline (136.881 us; speedup 1.0000x reference)
//
#include <hip/hip_runtime.h>
#include <math.h>

// VMamba discriminator forward. GEMMs: bf16 MFMA, pre-split weights (patch
// hi-only; in-proj/xproj hi/lo), A_p im2col materialized bf16, fp32 accum,
// XCD-local n-major decode. dwconv fused into build_xsT. Scan: chunk-parallel
// NC=32, states in regs, fused dt-proj, inline per-block prefix (no prefix
// kernel). Out-proj folded through w_eff. xs/ys/xc pipeline bf16.
// B=2, C=256, IMG=128, P=4 -> H=W=32, L=1024, D_INNER=512, N=16, R=16, K=4

typedef __attribute__((ext_vector_type(4))) float f32x4;
typedef __attribute__((ext_vector_type(8))) short bf16x8;

__device__ __forceinline__ ushort bf16_rn(float f) {
  uint u = __float_as_uint(f);
  return (ushort)((u + 0x7fffu + ((u >> 16) & 1u)) >> 16);
}
__device__ __forceinline__ float bf2f(uint us) { return __uint_as_float(us << 16); }
__device__ __forceinline__ uint packbf(float a, float b) {
  return (uint)bf16_rn(a) | ((uint)bf16_rn(b) << 16);
}

// ------ fused prep: im2col (blocks 0..2047) + weight splits + w_eff ---------
__global__ __launch_bounds__(256) void prep_kernel(const float* __restrict__ x,
    ushort* __restrict__ Ap,
    const float* __restrict__ pw, const float* __restrict__ iw,
    const float* __restrict__ ow, const float* __restrict__ xw,
    const float* __restrict__ hw,
    ushort* __restrict__ pwh,
    ushort* __restrict__ iwh, ushort* __restrict__ iwl,
    ushort* __restrict__ xwh, ushort* __restrict__ xwl,
    float* __restrict__ weff) {
  int bid = blockIdx.x;
  int tid = threadIdx.x;
  if (bid < 2048) {
    __shared__ __align__(16) ushort tile[32][136];
    int b = bid >> 10, hh = (bid >> 5) & 31, c0 = (bid & 31) * 8;
    int ci = tid >> 5, ph = (tid >> 3) & 3, w4 = tid & 7;
    const float* src = x + (((long)(b * 256 + c0 + ci) * 128 + 4 * hh + ph) * 128 + 16 * w4);
    #pragma unroll
    for (int j = 0; j < 4; ++j) {
      float4 v = *(const float4*)(src + 4 * j);
      uint2 pk;
      pk.x = packbf(v.x, v.y);
      pk.y = packbf(v.z, v.w);
      *(uint2*)&tile[w4 * 4 + j][ci * 16 + ph * 4] = pk;
    }
    __syncthreads();
    int w = tid >> 3;
    long rowbase = ((long)(b * 1024 + hh * 32 + w)) * 4096 + c0 * 16;
    #pragma unroll
    for (int i = 0; i < 2; ++i) {
      int gr = (tid & 7) + 8 * i;
      *(uint4*)&Ap[rowbase + gr * 8] = *(const uint4*)&tile[w][gr * 8];
    }
  } else {
    int i = (bid - 2048) * 256 + tid;
    if (i < 1048576) {               // patch weights: hi only
      pwh[i] = bf16_rn(pw[i]);
      return;
    }
    if (i < 1409024) {               // in_w / xproj_w: hi+lo split
      const float* src; ushort* hi; ushort* lo; int off;
      if (i < 1310720) { src = iw; hi = iwh; lo = iwl; off = i - 1048576; }
      else             { src = xw; hi = xwh; lo = xwl; off = i - 1310720; }
      float f = src[off];
      ushort h = bf16_rn(f);
      hi[off] = h;
      lo[off] = bf16_rn(f - __uint_as_float(((uint)h) << 16));
      return;
    }
    if (i < 1409536) {               // w_eff[k] = sum_c out_w[c][k]*hw[c]
      int k = i - 1409024;
      float s = 0.f;
      #pragma unroll 8
      for (int c = 0; c < 256; ++c) s += ow[c * 512 + k] * hw[c];
      weff[k] = s;
    }
  }
}

// ---------------- MFMA NT GEMM (bf16 A, hi[/lo] bf16 B, fp32 out) ------------
__global__ __launch_bounds__(512) void mfma_bf(
    const ushort* __restrict__ A, const ushort* __restrict__ Bhi,
    const ushort* __restrict__ Blo, float* __restrict__ Cout, float* __restrict__ C2,
    int M, int N, int K, int kchunk, int mode, int NBM, int NBZ, int uselo)
{
  __shared__ __align__(16) ushort Ah[128 * 64];
  __shared__ __align__(16) ushort Bh[64 * 64];
  __shared__ __align__(16) ushort Bl[64 * 64];
  int tid = threadIdx.x;
  int bid = blockIdx.x;
  int kz = bid % NBZ;
  int n0 = (bid / (NBZ * NBM)) * 64;
  int m0 = ((bid / NBZ) % NBM) * 128;
  int k0 = kz * kchunk;
  int wid = tid >> 6, lane = tid & 63;
  int wm = wid >> 1, wn = wid & 1;
  int lrow = lane & 15, g = lane >> 4;
  f32x4 acc[2][2] = {};
  int nkt = kchunk >> 6;
  for (int kt = 0; kt < nkt; ++kt) {
    int kb = k0 + (kt << 6);
    {
      int gi = tid & 7;
      #pragma unroll
      for (int i = 0; i < 2; ++i) {
        int row = (tid >> 3) + (i << 6);
        uint4 v = *(const uint4*)&A[(long)(m0 + row) * K + kb + gi * 8];
        *(uint4*)&Ah[row * 64 + ((gi ^ (row & 7)) << 3)] = v;
      }
      int row = tid >> 3;
      long off = (long)(n0 + row) * K + kb + gi * 8;
      int la = row * 64 + ((gi ^ (row & 7)) << 3);
      *(uint4*)&Bh[la] = *(const uint4*)&Bhi[off];
      if (uselo) *(uint4*)&Bl[la] = *(const uint4*)&Blo[off];
    }
    __syncthreads();
    #pragma unroll
    for (int kk = 0; kk < 2; ++kk) {
      bf16x8 af[2], bhf[2];
      #pragma unroll
      for (int mi = 0; mi < 2; ++mi) {
        int row = wm * 32 + mi * 16 + lrow;
        af[mi] = *(const bf16x8*)&Ah[row * 64 + ((((kk << 2) + g) ^ (row & 7)) << 3)];
      }
      #pragma unroll
      for (int ni = 0; ni < 2; ++ni) {
        int row = wn * 32 + ni * 16 + lrow;
        int col = (((kk << 2) + g) ^ (row & 7)) << 3;
        bhf[ni] = *(const bf16x8*)&Bh[row * 64 + col];
      }
      #pragma unroll
      for (int mi = 0; mi < 2; ++mi)
        #pragma unroll
        for (int ni = 0; ni < 2; ++ni)
          acc[mi][ni] = __builtin_amdgcn_mfma_f32_16x16x32_bf16(af[mi], bhf[ni], acc[mi][ni], 0, 0, 0);
      if (uselo) {
        #pragma unroll
        for (int ni = 0; ni < 2; ++ni) {
          int row = wn * 32 + ni * 16 + lrow;
          int col = (((kk << 2) + g) ^ (row & 7)) << 3;
          bf16x8 blf = *(const bf16x8*)&Bl[row * 64 + col];
          #pragma unroll
          for (int mi = 0; mi < 2; ++mi)
            acc[mi][ni] = __builtin_amdgcn_mfma_f32_16x16x32_bf16(af[mi], blf, acc[mi][ni], 0, 0, 0);
        }
      }
    }
    __syncthreads();
  }
  int r4 = lane >> 4;
  if (mode == 2) {
    bool xhalf = (n0 < 512);
    ushort* xcb = (ushort*)Cout;
    #pragma unroll
    for (int mi = 0; mi < 2; ++mi)
      #pragma unroll
      for (int ni = 0; ni < 2; ++ni) {
        int n = n0 + wn * 32 + ni * 16 + lrow;
        int mb = m0 + wm * 32 + mi * 16 + r4 * 4;
        int bb = mb >> 10, l = mb & 1023;
        if (xhalf) {
          uint2 o;
          o.x = packbf(acc[mi][ni][0], acc[mi][ni][1]);
          o.y = packbf(acc[mi][ni][2], acc[mi][ni][3]);
          *(uint2*)&xcb[((long)(bb * 512 + n)) * 1024 + l] = o;
        } else {
          #pragma unroll
          for (int r = 0; r < 4; ++r)
            C2[(long)(mb + r) * 512 + (n - 512)] = acc[mi][ni][r];
        }
      }
  } else {
    long zoff = (long)kz * M * N;
    #pragma unroll
    for (int mi = 0; mi < 2; ++mi)
      #pragma unroll
      for (int ni = 0; ni < 2; ++ni) {
        int n = n0 + wn * 32 + ni * 16 + lrow;
        int mb = m0 + wm * 32 + mi * 16 + r4 * 4;
        #pragma unroll
        for (int r = 0; r < 4; ++r)
          Cout[zoff + (long)(mb + r) * N + n] = acc[mi][ni][r];
      }
  }
}

// ---------------- MFMA x_dbl: xdbl[z] (1024,48) = xsT_bf[z] @ xproj[k]^T -----
__global__ __launch_bounds__(256) void mfma_x(
    const ushort* __restrict__ A, const ushort* __restrict__ Bhi,
    const ushort* __restrict__ Blo, float* __restrict__ xdbl)
{
  __shared__ __align__(16) ushort Ah[64 * 64];
  __shared__ __align__(16) ushort Bh[48 * 64];
  __shared__ __align__(16) ushort Bl[48 * 64];
  int tid = threadIdx.x;
  int m0 = blockIdx.x * 64;
  int z = blockIdx.y, k = z & 3;
  const ushort* Az = A + (long)z * 524288;
  const ushort* Bhz = Bhi + (long)k * 24576;
  const ushort* Blz = Blo + (long)k * 24576;
  int lane = tid & 63, wv = tid >> 6;
  int lrow = lane & 15, g = lane >> 4;
  f32x4 acc[3] = {};
  for (int kt = 0; kt < 8; ++kt) {
    int kb = kt << 6;
    #pragma unroll
    for (int i = 0; i < 2; ++i) {
      int idx = i * 256 + tid;
      int row = idx >> 3, gi = idx & 7;
      uint4 v = *(const uint4*)&Az[(long)(m0 + row) * 512 + kb + gi * 8];
      *(uint4*)&Ah[row * 64 + ((gi ^ (row & 7)) << 3)] = v;
      if (idx < 384) {
        long off = (long)row * 512 + kb + gi * 8;
        int la = row * 64 + ((gi ^ (row & 7)) << 3);
        *(uint4*)&Bh[la] = *(const uint4*)&Bhz[off];
        *(uint4*)&Bl[la] = *(const uint4*)&Blz[off];
      }
    }
    __syncthreads();
    #pragma unroll
    for (int kk = 0; kk < 2; ++kk) {
      int arow = wv * 16 + lrow;
      bf16x8 af = *(const bf16x8*)&Ah[arow * 64 + ((((kk << 2) + g) ^ (arow & 7)) << 3)];
      #pragma unroll
      for (int ni = 0; ni < 3; ++ni) {
        int brow = ni * 16 + lrow;
        int col = (((kk << 2) + g) ^ (brow & 7)) << 3;
        bf16x8 bh = *(const bf16x8*)&Bh[brow * 64 + col];
        bf16x8 bl = *(const bf16x8*)&Bl[brow * 64 + col];
        acc[ni] = __builtin_amdgcn_mfma_f32_16x16x32_bf16(af, bh, acc[ni], 0, 0, 0);
        acc[ni] = __builtin_amdgcn_mfma_f32_16x16x32_bf16(af, bl, acc[ni], 0, 0, 0);
      }
    }
    __syncthreads();
  }
  float* Cz = xdbl + (long)z * 49152;
  int r4 = lane >> 4;
  #pragma unroll
  for (int ni = 0; ni < 3; ++ni) {
    int n = ni * 16 + lrow;
    int mb = m0 + wv * 16 + r4 * 4;
    #pragma unroll
    for (int r = 0; r < 4; ++r)
      Cz[(long)(mb + r) * 48 + n] = acc[ni][r];
  }
}

// ---------------- block reduce helpers (256 threads) ----------------
__device__ __forceinline__ float blk_sum(float v, float* sm) {
  #pragma unroll
  for (int o = 32; o > 0; o >>= 1) v += __shfl_down(v, o);
  int wid = threadIdx.x >> 6, lane = threadIdx.x & 63;
  __syncthreads();
  if (lane == 0) sm[wid] = v;
  __syncthreads();
  return sm[0] + sm[1] + sm[2] + sm[3];
}
__device__ __forceinline__ void blk_sum2(float& a, float& b, float* sm) {
  #pragma unroll
  for (int o = 32; o > 0; o >>= 1) { a += __shfl_down(a, o); b += __shfl_down(b, o); }
  int wid = threadIdx.x >> 6, lane = threadIdx.x & 63;
  __syncthreads();
  if (lane == 0) { sm[wid * 2] = a; sm[wid * 2 + 1] = b; }
  __syncthreads();
  a = sm[0] + sm[2] + sm[4] + sm[6];
  b = sm[1] + sm[3] + sm[5] + sm[7];
}
__device__ __forceinline__ void blk_sum3(float& a, float& b, float& c, float* sm) {
  #pragma unroll
  for (int o = 32; o > 0; o >>= 1) {
    a += __shfl_down(a, o); b += __shfl_down(b, o); c += __shfl_down(c, o);
  }
  int wid = threadIdx.x >> 6, lane = threadIdx.x & 63;
  __syncthreads();
  if (lane == 0) { sm[wid * 3] = a; sm[wid * 3 + 1] = b; sm[wid * 3 + 2] = c; }
  __syncthreads();
  a = sm[0] + sm[3] + sm[6] + sm[9];
  b = sm[1] + sm[4] + sm[7] + sm[10];
  c = sm[2] + sm[5] + sm[8] + sm[11];
}

// -- fused: patch split-K(8) reduce + bias -> LN1 -> u (bf16); tpart head ----
__global__ __launch_bounds__(256) void reduce_ln1(const float* __restrict__ P,
    const float* __restrict__ bias, const float* __restrict__ g,
    const float* __restrict__ b, ushort* __restrict__ u,
    const float* __restrict__ hw, float* __restrict__ tpart) {
  __shared__ float sm[12];
  int m = blockIdx.x, c = threadIdx.x;
  float v = bias[c];
  #pragma unroll
  for (int s = 0; s < 8; ++s) v += P[(long)s * 524288 + m * 256 + c];
  float s1 = v, s2 = v * v, s3 = v * hw[c];
  blk_sum3(s1, s2, s3, sm);
  if (c == 0) tpart[m] = s3;
  float mu = s1 * (1.f / 256.f);
  float var = s2 * (1.f / 256.f) - mu * mu;
  float rs = rsqrtf(var + 1e-5f);
  u[(long)m * 256 + c] = bf16_rn((v - mu) * rs * g[c] + b[c]);
}

// ---------------- head final ----------------
__global__ __launch_bounds__(256) void head_final(const float* __restrict__ tpart,
    const float* __restrict__ spart, const float* __restrict__ hb,
    float* __restrict__ out) {
  __shared__ float sm[4];
  int b = blockIdx.x, tid = threadIdx.x;
  float s = 0.f;
  #pragma unroll
  for (int j = 0; j < 4; ++j) {
    int m = b * 1024 + tid * 4 + j;
    s += tpart[m] + spart[m];
  }
  float tot = blk_sum(s, sm);
  if (tid == 0) out[b] = tot * (1.f / 1024.f) + hb[0];
}

// -- fused dwconv(3x3 dw + bias + silu) + build_xsT: xc_bf -> xsT_bf ---------
__global__ __launch_bounds__(256) void dwbuild(const ushort* __restrict__ xc,
    const float* __restrict__ cw, const float* __restrict__ cb,
    ushort* __restrict__ xsTb) {
  __shared__ float pl[3][32][33];
  __shared__ ushort tile[32][34];
  int h = blockIdx.x;
  int d0 = blockIdx.y * 32;
  int z = blockIdx.z;
  int b = z >> 2, k = z & 3;
  int tid = threadIdx.x;
  int dd = tid >> 3, w4 = (tid & 7) * 4;
  #pragma unroll
  for (int r = 0; r < 3; ++r) {
    int hh = h - 1 + r;
    float4 vv = make_float4(0.f, 0.f, 0.f, 0.f);
    if (hh >= 0 && hh < 32) {
      uint2 v = *(const uint2*)&xc[((long)(b * 512 + d0 + dd)) * 1024 + hh * 32 + w4];
      vv.x = bf2f(v.x & 0xffff); vv.y = bf2f(v.x >> 16);
      vv.z = bf2f(v.y & 0xffff); vv.w = bf2f(v.y >> 16);
    }
    pl[r][dd][w4] = vv.x; pl[r][dd][w4 + 1] = vv.y;
    pl[r][dd][w4 + 2] = vv.z; pl[r][dd][w4 + 3] = vv.w;
  }
  float w9[9];
  #pragma unroll
  for (int i = 0; i < 9; ++i) w9[i] = cw[(d0 + dd) * 9 + i];
  float bias = cb[d0 + dd];
  __syncthreads();
  #pragma unroll
  for (int j = 0; j < 4; ++j) {
    int w = w4 + j;
    float acc = 0.f;
    #pragma unroll
    for (int r = 0; r < 3; ++r) {
      if (w > 0)  acc += w9[r * 3 + 0] * pl[r][dd][w - 1];
      acc += w9[r * 3 + 1] * pl[r][dd][w];
      if (w < 31) acc += w9[r * 3 + 2] * pl[r][dd][w + 1];
    }
    acc += bias;
    tile[dd][w] = bf16_rn(acc / (1.f + __expf(-acc)));   // silu
  }
  __syncthreads();
  int a = tid >> 5, q = tid & 31;
  #pragma unroll
  for (int i = 0; i < 4; ++i) {
    int w = a + i * 8;
    int r;
    if (k == 0) r = h * 32 + w;
    else if (k == 1) r = w * 32 + h;
    else if (k == 2) r = 1023 - (h * 32 + w);
    else r = 1023 - (w * 32 + h);
    xsTb[((long)z * 1024 + r) * 512 + d0 + q] = tile[q][w];
  }
}

// ------- chunk-parallel selective scan, NC=32, fused dt-projection ----------
// FINAL computes its own h_in inline from (dsum, hp) of chunks < c.
template<bool FINAL>
__global__ __launch_bounds__(128) void scan_chunk7(
    const float* __restrict__ xdbl, ushort* xsb,
    const float* __restrict__ dtw, const float* __restrict__ dtb,
    const float* __restrict__ A_log, const float* __restrict__ Ds,
    float* __restrict__ dsum, float* __restrict__ hpb)
{
  __shared__ float sdt[32][64];
  __shared__ float sxv[16][64];
  __shared__ float sy[16][64];        // first 2KB aliased as sR during dt-calc
  __shared__ float sBC[32][32];
  float (*sR)[16] = (float(*)[16])sy;
  int tid = threadIdx.x;
  int dl = tid >> 1, ng = tid & 1;
  int d0 = blockIdx.x * 64;
  int d = d0 + dl;
  int c = blockIdx.y;
  int z = blockIdx.z;
  int k = z & 3;
  long baseD = (long)z * 524288;
  int l0 = c * 32;
  const float* xdz = xdbl + (long)z * 49152 + (long)l0 * 48;
  // stage B/C + R
  #pragma unroll
  for (int i = 0; i < 2; ++i) {
    int idx = i * 128 + tid;
    int l = idx >> 3, q = idx & 7;
    *(float4*)&sBC[l][q * 4] = *(const float4*)(xdz + l * 48 + 16 + q * 4);
  }
  {
    int l = tid >> 2, q = tid & 3;
    *(float4*)&sR[l][q * 4] = *(const float4*)(xdz + l * 48 + q * 4);
  }
  // prefetch first xs tile early (hides under dt compute)
  int xli = tid >> 3;
  int xdj = (tid & 7) * 8;
  uint4 rxv = *(const uint4*)&xsb[baseD + (long)(l0 + xli) * 512 + d0 + xdj];
  float a[8], h[8];
  #pragma unroll
  for (int j = 0; j < 8; ++j) {
    a[j] = -__expf(A_log[((long)k * 512 + d) * 16 + ng * 8 + j]);
    h[j] = 0.f;
  }
  float4 wr0 = *(const float4*)(dtw + ((long)k * 512 + d) * 16);
  float4 wr1 = *(const float4*)(dtw + ((long)k * 512 + d) * 16 + 4);
  float4 wr2 = *(const float4*)(dtw + ((long)k * 512 + d) * 16 + 8);
  float4 wr3 = *(const float4*)(dtw + ((long)k * 512 + d) * 16 + 12);
  float dbias = dtb[k * 512 + d];
  float Dv = 0.f;
  if (FINAL) {
    Dv = Ds[k * 512 + d];
    // inline prefix over chunks j < c (same fold order as old scan_prefix)
    for (int j = 0; j < c; ++j) {
      float ds = dsum[j * 4096 + z * 512 + d];
      int gb = j * 65536 + z * 8192 + d * 16 + ng * 8;
      float4 hpa = *(const float4*)(hpb + gb);
      float4 hpbv = *(const float4*)(hpb + gb + 4);
      h[0] = __expf(ds * a[0]) * h[0] + hpa.x;
      h[1] = __expf(ds * a[1]) * h[1] + hpa.y;
      h[2] = __expf(ds * a[2]) * h[2] + hpa.z;
      h[3] = __expf(ds * a[3]) * h[3] + hpa.w;
      h[4] = __expf(ds * a[4]) * h[4] + hpbv.x;
      h[5] = __expf(ds * a[5]) * h[5] + hpbv.y;
      h[6] = __expf(ds * a[6]) * h[6] + hpbv.z;
      h[7] = __expf(ds * a[7]) * h[7] + hpbv.w;
    }
  }
  __syncthreads();                 // sR ready
  #pragma unroll
  for (int li = 0; li < 16; ++li) {
    int l = ng * 16 + li;
    const float* rr = &sR[l][0];
    float acc = dbias;
    acc += wr0.x * rr[0];  acc += wr0.y * rr[1];  acc += wr0.z * rr[2];  acc += wr0.w * rr[3];
    acc += wr1.x * rr[4];  acc += wr1.y * rr[5];  acc += wr1.z * rr[6];  acc += wr1.w * rr[7];
    acc += wr2.x * rr[8];  acc += wr2.y * rr[9];  acc += wr2.z * rr[10]; acc += wr2.w * rr[11];
    acc += wr3.x * rr[12]; acc += wr3.y * rr[13]; acc += wr3.z * rr[14]; acc += wr3.w * rr[15];
    sdt[l][dl] = (acc > 20.f) ? acc : __logf(1.f + __expf(acc));
  }
  __syncthreads();                 // sdt ready; sR dead -> sy writable
  float dtsum = 0.f;
  for (int t = 0; t < 2; ++t) {
    {
      float4 f0, f1;
      f0.x = bf2f(rxv.x & 0xffff); f0.y = bf2f(rxv.x >> 16);
      f0.z = bf2f(rxv.y & 0xffff); f0.w = bf2f(rxv.y >> 16);
      f1.x = bf2f(rxv.z & 0xffff); f1.y = bf2f(rxv.z >> 16);
      f1.z = bf2f(rxv.w & 0xffff); f1.w = bf2f(rxv.w >> 16);
      *(float4*)&sxv[xli][xdj] = f0;
      *(float4*)&sxv[xli][xdj + 4] = f1;
    }
    __syncthreads();
    if (t == 0)
      rxv = *(const uint4*)&xsb[baseD + (long)(l0 + 16 + xli) * 512 + d0 + xdj];
    #pragma unroll
    for (int li = 0; li < 16; ++li) {
      int lr = t * 16 + li;
      float dt = sdt[lr][dl];
      float xv = sxv[li][dl];
      float w = dt * xv;
      float4 B0 = *(const float4*)&sBC[lr][ng * 8];
      float4 B1 = *(const float4*)&sBC[lr][ng * 8 + 4];
      if (!FINAL) {
        dtsum += dt;
        h[0] = __expf(dt * a[0]) * h[0] + w * B0.x;
        h[1] = __expf(dt * a[1]) * h[1] + w * B0.y;
        h[2] = __expf(dt * a[2]) * h[2] + w * B0.z;
        h[3] = __expf(dt * a[3]) * h[3] + w * B0.w;
        h[4] = __expf(dt * a[4]) * h[4] + w * B1.x;
        h[5] = __expf(dt * a[5]) * h[5] + w * B1.y;
        h[6] = __expf(dt * a[6]) * h[6] + w * B1.z;
        h[7] = __expf(dt * a[7]) * h[7] + w * B1.w;
      } else {
        float4 C0 = *(const float4*)&sBC[lr][16 + ng * 8];
        float4 C1 = *(const float4*)&sBC[lr][16 + ng * 8 + 4];
        float p;
        h[0] = __expf(dt * a[0]) * h[0] + w * B0.x; p  = h[0] * C0.x;
        h[1] = __expf(dt * a[1]) * h[1] + w * B0.y; p += h[1] * C0.y;
        h[2] = __expf(dt * a[2]) * h[2] + w * B0.z; p += h[2] * C0.z;
        h[3] = __expf(dt * a[3]) * h[3] + w * B0.w; p += h[3] * C0.w;
        h[4] = __expf(dt * a[4]) * h[4] + w * B1.x; p += h[4] * C1.x;
        h[5] = __expf(dt * a[5]) * h[5] + w * B1.y; p += h[5] * C1.y;
        h[6] = __expf(dt * a[6]) * h[6] + w * B1.z; p += h[6] * C1.z;
        h[7] = __expf(dt * a[7]) * h[7] + w * B1.w; p += h[7] * C1.w;
        p += __shfl_xor(p, 1);
        if (ng == 0) sy[li][dl] = p + Dv * xv;
      }
    }
    __syncthreads();
    if (FINAL) {
      float4 f0 = *(float4*)&sy[xli][xdj];
      float4 f1 = *(float4*)&sy[xli][xdj + 4];
      uint4 o;
      o.x = packbf(f0.x, f0.y); o.y = packbf(f0.z, f0.w);
      o.z = packbf(f1.x, f1.y); o.w = packbf(f1.z, f1.w);
      *(uint4*)&xsb[baseD + (long)(l0 + t * 16 + xli) * 512 + d0 + xdj] = o;
    }
  }
  if (!FINAL) {
    int gbase = c * 65536 + z * 8192 + d * 16 + ng * 8;
    *(float4*)(hpb + gbase)     = make_float4(h[0], h[1], h[2], h[3]);
    *(float4*)(hpb + gbase + 4) = make_float4(h[4], h[5], h[6], h[7]);
    if (ng == 0) dsum[c * 4096 + z * 512 + d] = dtsum;
  }
}

// -- fused: combine 4 dirs (bf16) + LN(512) + silu(z) gate + head dot --------
__global__ __launch_bounds__(256) void combine_ln2gate(const ushort* __restrict__ ys,
    const float* __restrict__ zb, const float* __restrict__ g,
    const float* __restrict__ b, const float* __restrict__ weff,
    float* __restrict__ spart) {
  __shared__ float sm[8];
  int m = blockIdx.x, tid = threadIdx.x;
  int bb = m >> 10, l = m & 1023;
  int hh = l >> 5, w = l & 31;
  int lw = w * 32 + hh;
  long b4 = (long)bb * 4;
  uint u0 = *(const uint*)&ys[((b4 + 0) * 1024 + l) * 512 + tid * 2];
  uint u1 = *(const uint*)&ys[((b4 + 2) * 1024 + (1023 - l)) * 512 + tid * 2];
  uint u2 = *(const uint*)&ys[((b4 + 1) * 1024 + lw) * 512 + tid * 2];
  uint u3 = *(const uint*)&ys[((b4 + 3) * 1024 + (1023 - lw)) * 512 + tid * 2];
  float v0 = bf2f(u0 & 0xffff) + bf2f(u1 & 0xffff) + bf2f(u2 & 0xffff) + bf2f(u3 & 0xffff);
  float v1 = bf2f(u0 >> 16) + bf2f(u1 >> 16) + bf2f(u2 >> 16) + bf2f(u3 >> 16);
  float s1 = v0 + v1, s2 = v0 * v0 + v1 * v1;
  blk_sum2(s1, s2, sm);
  float mu = s1 * (1.f / 512.f);
  float var = s2 * (1.f / 512.f) - mu * mu;
  float rs = rsqrtf(var + 1e-5f);
  float2 gg = *(const float2*)(g + tid * 2);
  float2 bbv = *(const float2*)(b + tid * 2);
  float2 zz = *(const float2*)(zb + (long)m * 512 + tid * 2);
  float y0 = ((v0 - mu) * rs * gg.x + bbv.x) * (zz.x / (1.f + __expf(-zz.x)));
  float y1 = ((v1 - mu) * rs * gg.y + bbv.y) * (zz.y / (1.f + __expf(-zz.y)));
  float2 we = *(const float2*)(weff + tid * 2);
  float s3 = blk_sum(y0 * we.x + y1 * we.y, sm);
  if (tid == 0) spart[m] = s3;
}

extern "C" void kernel_launch(void* const* d_in, const int* in_sizes, int n_in,
                              void* d_out, int out_size, void* d_ws, size_t ws_size,
                              hipStream_t stream) {
  const float* x       = (const float*)d_in[0];
  const float* patch_w = (const float*)d_in[1];
  const float* patch_b = (const float*)d_in[2];
  const float* ln_g    = (const float*)d_in[3];
  const float* ln_b    = (const float*)d_in[4];
  const float* in_w    = (const float*)d_in[5];
  const float* conv_w  = (const float*)d_in[6];
  const float* conv_b  = (const float*)d_in[7];
  const float* xproj_w = (const float*)d_in[8];
  const float* dt_w    = (const float*)d_in[9];
  const float* dt_b    = (const float*)d_in[10];
  const float* A_log   = (const float*)d_in[11];
  const float* Ds      = (const float*)d_in[12];
  const float* on_g    = (const float*)d_in[13];
  const float* on_b    = (const float*)d_in[14];
  const float* out_w   = (const float*)d_in[15];
  const float* head_w  = (const float*)d_in[16];
  const float* head_b  = (const float*)d_in[17];

  float* ws = (float*)d_ws;
  float*  tpart   = ws;                        // 2048
  float*  spart   = ws + 2048;                 // 2048
  float*  weff_buf= ws + 4096;                 // 512
  float*  z_buf   = ws + 8192;                 // 1048576 f
  ushort* u_bf    = (ushort*)(ws + 1056768);   // 262144 f
  ushort* xc_bf   = (ushort*)(ws + 1318912);   // 524288 f
  ushort* xsT_bf  = (ushort*)(ws + 1843200);   // 2097152 f
  float*  xdbl_buf= ws + 3940352;              // 393216 f
  float*  P_patch = ws + 4333568;              // 8*524288 = 4194304 f
  float*  dsum_buf= ws + 8527872;              // 131072 f
  float*  hp_buf  = ws + 8658944;              // 2097152 f
  ushort* A_p     = (ushort*)(ws + 10756096);  // 4194304 f
  ushort* pw_hi   = (ushort*)(ws + 14950400);  // 524288 f
  ushort* iw_hi   = (ushort*)(ws + 15474688);  // 131072 f
  ushort* iw_lo   = (ushort*)(ws + 15605760);
  ushort* xw_hi   = (ushort*)(ws + 15736832);  // 49152 f
  ushort* xw_lo   = (ushort*)(ws + 15785984);
  // high-water ~ 15.8M floats ~ 63 MB

  // 0. fused prep: im2col A_p + weight splits (patch hi-only) + w_eff
  prep_kernel<<<7554, 256, 0, stream>>>(x, A_p, patch_w, in_w, out_w, xproj_w,
      head_w, pw_hi, iw_hi, iw_lo, xw_hi, xw_lo, weff_buf);
  // 1. patch embed MFMA (hi-only), split-K=8 -> partials (2 blocks/CU)
  mfma_bf<<<512, 512, 0, stream>>>(A_p, pw_hi, nullptr, P_patch, nullptr,
      2048, 256, 4096, 512, 0, 16, 8, 0);
  // 2. fused reduce + bias + LN1 -> u (bf16); tpart head partial
  reduce_ln1<<<2048, 256, 0, stream>>>(P_patch, patch_b, ln_g, ln_b, u_bf,
      head_w, tpart);
  // 3. in-proj MFMA fused epilogue: xc (transposed bf16) + z (f32)
  mfma_bf<<<256, 512, 0, stream>>>(u_bf, iw_hi, iw_lo, (float*)xc_bf, z_buf,
      2048, 1024, 256, 256, 2, 16, 1, 1);
  // 4. fused depthwise conv + silu + build xsT (bf16, 4 directions)
  dwbuild<<<dim3(32, 16, 8), 256, 0, stream>>>(xc_bf, conv_w, conv_b, xsT_bf);
  // 5. x_dbl[z] (1024,48) = xsT_bf[z] @ xproj[k]^T (MFMA)
  mfma_x<<<dim3(16, 8), 256, 0, stream>>>(xsT_bf, xw_hi, xw_lo, xdbl_buf);
  // 6. chunk-parallel selective scan (NC=32, fused dt-proj, inline prefix)
  scan_chunk7<false><<<dim3(8, 32, 8), 128, 0, stream>>>(xdbl_buf, xsT_bf,
      dt_w, dt_b, A_log, Ds, dsum_buf, hp_buf);
  scan_chunk7<true><<<dim3(8, 32, 8), 128, 0, stream>>>(xdbl_buf, xsT_bf,
      dt_w, dt_b, A_log, Ds, dsum_buf, hp_buf);
  // 7. fused combine + LN2 + silu gate + head dot -> spart
  combine_ln2gate<<<2048, 256, 0, stream>>>(xsT_bf, z_buf, on_g, on_b,
      weff_buf, spart);
  // 8. head final
  head_final<<<2, 256, 0, stream>>>(tpart, spart, head_b, (float*)d_out);
}

// Round 17
// 128.350 us; speedup vs baseline: 1.0665x; 1.0665x over previous
//
#include <hip/hip_runtime.h>
#include <math.h>

// VMamba discriminator forward. GEMMs: bf16 MFMA (patch: hi-only weights;
// others: hi/lo split), activations bf16-hi, fp32 accum, XCD-local n-major
// block decode. Scan: chunk-parallel NC=32, states in regs, fused dt-proj,
// dtsum-compressed prefix; xs/ys/xc pipeline bf16. Head folded into reduces.
// B=2, C=256, IMG=128, P=4 -> H=W=32, L=1024, D_INNER=512, N=16, R=16, K=4

typedef __attribute__((ext_vector_type(4))) float f32x4;
typedef __attribute__((ext_vector_type(8))) short bf16x8;

__device__ __forceinline__ ushort bf16_rn(float f) {
  uint u = __float_as_uint(f);
  return (ushort)((u + 0x7fffu + ((u >> 16) & 1u)) >> 16);
}
__device__ __forceinline__ float bf2f(uint us) { return __uint_as_float(us << 16); }
__device__ __forceinline__ uint packbf(float a, float b) {
  return (uint)bf16_rn(a) | ((uint)bf16_rn(b) << 16);
}

// ------ fused prep: im2col (blocks 0..2047) + weight splits (rest) ----------
__global__ __launch_bounds__(256) void prep_kernel(const float* __restrict__ x,
    ushort* __restrict__ Ap,
    const float* __restrict__ pw, const float* __restrict__ iw,
    const float* __restrict__ ow, const float* __restrict__ xw,
    ushort* __restrict__ pwh,
    ushort* __restrict__ iwh, ushort* __restrict__ iwl,
    ushort* __restrict__ owh, ushort* __restrict__ owl,
    ushort* __restrict__ xwh, ushort* __restrict__ xwl) {
  int bid = blockIdx.x;
  int tid = threadIdx.x;
  if (bid < 2048) {
    __shared__ __align__(16) ushort tile[32][136];
    int b = bid >> 10, hh = (bid >> 5) & 31, c0 = (bid & 31) * 8;
    int ci = tid >> 5, ph = (tid >> 3) & 3, w4 = tid & 7;
    const float* src = x + (((long)(b * 256 + c0 + ci) * 128 + 4 * hh + ph) * 128 + 16 * w4);
    #pragma unroll
    for (int j = 0; j < 4; ++j) {
      float4 v = *(const float4*)(src + 4 * j);
      uint2 pk;
      pk.x = packbf(v.x, v.y);
      pk.y = packbf(v.z, v.w);
      *(uint2*)&tile[w4 * 4 + j][ci * 16 + ph * 4] = pk;
    }
    __syncthreads();
    int w = tid >> 3;
    long rowbase = ((long)(b * 1024 + hh * 32 + w)) * 4096 + c0 * 16;
    #pragma unroll
    for (int i = 0; i < 2; ++i) {
      int gr = (tid & 7) + 8 * i;
      *(uint4*)&Ap[rowbase + gr * 8] = *(const uint4*)&tile[w][gr * 8];
    }
  } else {
    int i = (bid - 2048) * 256 + tid;
    if (i < 1048576) {               // patch weights: hi only
      pwh[i] = bf16_rn(pw[i]);
      return;
    }
    const float* src; ushort* hi; ushort* lo; int off;
    if (i < 1310720)      { src = iw; hi = iwh; lo = iwl; off = i - 1048576; }
    else if (i < 1441792) { src = ow; hi = owh; lo = owl; off = i - 1310720; }
    else if (i < 1540096) { src = xw; hi = xwh; lo = xwl; off = i - 1441792; }
    else return;
    float f = src[off];
    ushort h = bf16_rn(f);
    hi[off] = h;
    lo[off] = bf16_rn(f - __uint_as_float(((uint)h) << 16));
  }
}

// ---------------- MFMA NT GEMM (bf16 A, hi[/lo] bf16 B, fp32 out) ------------
// 1D grid, n-major decode: id = n*NBM*NBZ + m*NBZ + z (XCD-local A reuse).
// mode 0: split-K partials. mode 2: in-proj fused epilogue (xc bf16 + z f32).
__global__ __launch_bounds__(512) void mfma_bf(
    const ushort* __restrict__ A, const ushort* __restrict__ Bhi,
    const ushort* __restrict__ Blo, float* __restrict__ Cout, float* __restrict__ C2,
    int M, int N, int K, int kchunk, int mode, int NBM, int NBZ, int uselo)
{
  __shared__ __align__(16) ushort Ah[128 * 64];
  __shared__ __align__(16) ushort Bh[64 * 64];
  __shared__ __align__(16) ushort Bl[64 * 64];
  int tid = threadIdx.x;
  int bid = blockIdx.x;
  int kz = bid % NBZ;
  int n0 = (bid / (NBZ * NBM)) * 64;
  int m0 = ((bid / NBZ) % NBM) * 128;
  int k0 = kz * kchunk;
  int wid = tid >> 6, lane = tid & 63;
  int wm = wid >> 1, wn = wid & 1;
  int lrow = lane & 15, g = lane >> 4;
  f32x4 acc[2][2] = {};
  int nkt = kchunk >> 6;
  for (int kt = 0; kt < nkt; ++kt) {
    int kb = k0 + (kt << 6);
    {
      int gi = tid & 7;
      #pragma unroll
      for (int i = 0; i < 2; ++i) {
        int row = (tid >> 3) + (i << 6);
        uint4 v = *(const uint4*)&A[(long)(m0 + row) * K + kb + gi * 8];
        *(uint4*)&Ah[row * 64 + ((gi ^ (row & 7)) << 3)] = v;
      }
      int row = tid >> 3;
      long off = (long)(n0 + row) * K + kb + gi * 8;
      int la = row * 64 + ((gi ^ (row & 7)) << 3);
      *(uint4*)&Bh[la] = *(const uint4*)&Bhi[off];
      if (uselo) *(uint4*)&Bl[la] = *(const uint4*)&Blo[off];
    }
    __syncthreads();
    #pragma unroll
    for (int kk = 0; kk < 2; ++kk) {
      bf16x8 af[2], bhf[2];
      #pragma unroll
      for (int mi = 0; mi < 2; ++mi) {
        int row = wm * 32 + mi * 16 + lrow;
        af[mi] = *(const bf16x8*)&Ah[row * 64 + ((((kk << 2) + g) ^ (row & 7)) << 3)];
      }
      #pragma unroll
      for (int ni = 0; ni < 2; ++ni) {
        int row = wn * 32 + ni * 16 + lrow;
        int col = (((kk << 2) + g) ^ (row & 7)) << 3;
        bhf[ni] = *(const bf16x8*)&Bh[row * 64 + col];
      }
      #pragma unroll
      for (int mi = 0; mi < 2; ++mi)
        #pragma unroll
        for (int ni = 0; ni < 2; ++ni)
          acc[mi][ni] = __builtin_amdgcn_mfma_f32_16x16x32_bf16(af[mi], bhf[ni], acc[mi][ni], 0, 0, 0);
      if (uselo) {
        #pragma unroll
        for (int ni = 0; ni < 2; ++ni) {
          int row = wn * 32 + ni * 16 + lrow;
          int col = (((kk << 2) + g) ^ (row & 7)) << 3;
          bf16x8 blf = *(const bf16x8*)&Bl[row * 64 + col];
          #pragma unroll
          for (int mi = 0; mi < 2; ++mi)
            acc[mi][ni] = __builtin_amdgcn_mfma_f32_16x16x32_bf16(af[mi], blf, acc[mi][ni], 0, 0, 0);
        }
      }
    }
    __syncthreads();
  }
  int r4 = lane >> 4;
  if (mode == 2) {
    bool xhalf = (n0 < 512);
    ushort* xcb = (ushort*)Cout;
    #pragma unroll
    for (int mi = 0; mi < 2; ++mi)
      #pragma unroll
      for (int ni = 0; ni < 2; ++ni) {
        int n = n0 + wn * 32 + ni * 16 + lrow;
        int mb = m0 + wm * 32 + mi * 16 + r4 * 4;
        int bb = mb >> 10, l = mb & 1023;
        if (xhalf) {
          uint2 o;
          o.x = packbf(acc[mi][ni][0], acc[mi][ni][1]);
          o.y = packbf(acc[mi][ni][2], acc[mi][ni][3]);
          *(uint2*)&xcb[((long)(bb * 512 + n)) * 1024 + l] = o;
        } else {
          #pragma unroll
          for (int r = 0; r < 4; ++r)
            C2[(long)(mb + r) * 512 + (n - 512)] = acc[mi][ni][r];
        }
      }
  } else {
    long zoff = (long)kz * M * N;
    #pragma unroll
    for (int mi = 0; mi < 2; ++mi)
      #pragma unroll
      for (int ni = 0; ni < 2; ++ni) {
        int n = n0 + wn * 32 + ni * 16 + lrow;
        int mb = m0 + wm * 32 + mi * 16 + r4 * 4;
        #pragma unroll
        for (int r = 0; r < 4; ++r)
          Cout[zoff + (long)(mb + r) * N + n] = acc[mi][ni][r];
      }
  }
}

// ---------------- MFMA x_dbl: xdbl[z] (1024,48) = xsT_bf[z] @ xproj[k]^T -----
__global__ __launch_bounds__(256) void mfma_x(
    const ushort* __restrict__ A, const ushort* __restrict__ Bhi,
    const ushort* __restrict__ Blo, float* __restrict__ xdbl)
{
  __shared__ __align__(16) ushort Ah[64 * 64];
  __shared__ __align__(16) ushort Bh[48 * 64];
  __shared__ __align__(16) ushort Bl[48 * 64];
  int tid = threadIdx.x;
  int m0 = blockIdx.x * 64;
  int z = blockIdx.y, k = z & 3;
  const ushort* Az = A + (long)z * 524288;
  const ushort* Bhz = Bhi + (long)k * 24576;
  const ushort* Blz = Blo + (long)k * 24576;
  int lane = tid & 63, wv = tid >> 6;
  int lrow = lane & 15, g = lane >> 4;
  f32x4 acc[3] = {};
  for (int kt = 0; kt < 8; ++kt) {
    int kb = kt << 6;
    #pragma unroll
    for (int i = 0; i < 2; ++i) {
      int idx = i * 256 + tid;
      int row = idx >> 3, gi = idx & 7;
      uint4 v = *(const uint4*)&Az[(long)(m0 + row) * 512 + kb + gi * 8];
      *(uint4*)&Ah[row * 64 + ((gi ^ (row & 7)) << 3)] = v;
      if (idx < 384) {
        long off = (long)row * 512 + kb + gi * 8;
        int la = row * 64 + ((gi ^ (row & 7)) << 3);
        *(uint4*)&Bh[la] = *(const uint4*)&Bhz[off];
        *(uint4*)&Bl[la] = *(const uint4*)&Blz[off];
      }
    }
    __syncthreads();
    #pragma unroll
    for (int kk = 0; kk < 2; ++kk) {
      int arow = wv * 16 + lrow;
      bf16x8 af = *(const bf16x8*)&Ah[arow * 64 + ((((kk << 2) + g) ^ (arow & 7)) << 3)];
      #pragma unroll
      for (int ni = 0; ni < 3; ++ni) {
        int brow = ni * 16 + lrow;
        int col = (((kk << 2) + g) ^ (brow & 7)) << 3;
        bf16x8 bh = *(const bf16x8*)&Bh[brow * 64 + col];
        bf16x8 bl = *(const bf16x8*)&Bl[brow * 64 + col];
        acc[ni] = __builtin_amdgcn_mfma_f32_16x16x32_bf16(af, bh, acc[ni], 0, 0, 0);
        acc[ni] = __builtin_amdgcn_mfma_f32_16x16x32_bf16(af, bl, acc[ni], 0, 0, 0);
      }
    }
    __syncthreads();
  }
  float* Cz = xdbl + (long)z * 49152;
  int r4 = lane >> 4;
  #pragma unroll
  for (int ni = 0; ni < 3; ++ni) {
    int n = ni * 16 + lrow;
    int mb = m0 + wv * 16 + r4 * 4;
    #pragma unroll
    for (int r = 0; r < 4; ++r)
      Cz[(long)(mb + r) * 48 + n] = acc[ni][r];
  }
}

// ---------------- block reduce helper (256 threads) ----------------
__device__ __forceinline__ float blk_sum(float v, float* sm) {
  #pragma unroll
  for (int o = 32; o > 0; o >>= 1) v += __shfl_down(v, o);
  int wid = threadIdx.x >> 6, lane = threadIdx.x & 63;
  __syncthreads();
  if (lane == 0) sm[wid] = v;
  __syncthreads();
  int nw = blockDim.x >> 6;
  float r = 0.f;
  for (int i = 0; i < nw; ++i) r += sm[i];
  return r;
}

// -- fused: patch split-K reduce + bias -> LN1 -> u (bf16); t never stored; --
// -- head partial tpart[m] = sum_c t[m,c]*hw[c] ------------------------------
__global__ __launch_bounds__(256) void reduce_ln1(const float* __restrict__ P,
    const float* __restrict__ bias, const float* __restrict__ g,
    const float* __restrict__ b, ushort* __restrict__ u,
    const float* __restrict__ hw, float* __restrict__ tpart) {
  __shared__ float sm[8];
  int m = blockIdx.x, c = threadIdx.x;
  float v = bias[c];
  #pragma unroll
  for (int s = 0; s < 8; ++s) v += P[(long)s * 524288 + m * 256 + c];
  float s1 = blk_sum(v, sm);
  float s2 = blk_sum(v * v, sm);
  float s3 = blk_sum(v * hw[c], sm);
  if (c == 0) tpart[m] = s3;
  float mu = s1 * (1.f / 256.f);
  float var = s2 * (1.f / 256.f) - mu * mu;
  float rs = rsqrtf(var + 1e-5f);
  u[(long)m * 256 + c] = bf16_rn((v - mu) * rs * g[c] + b[c]);
}

// -- out-proj split-K reduce fused with head dot: spart[bid] = sum ss*hw -----
__global__ __launch_bounds__(256) void reduce_ss(const float* __restrict__ P,
    const float* __restrict__ hw, float* __restrict__ spart) {
  __shared__ float sm[8];
  int bid = blockIdx.x;                       // 512 blocks x 1024 elems
  int i = bid * 1024 + threadIdx.x * 4;       // element; c = i & 255
  float4 v = make_float4(0.f, 0.f, 0.f, 0.f);
  #pragma unroll
  for (int s = 0; s < 4; ++s) {
    float4 p = *(const float4*)(P + (long)s * 524288 + i);
    v.x += p.x; v.y += p.y; v.z += p.z; v.w += p.w;
  }
  float4 w = *(const float4*)(hw + (i & 255));
  float s = v.x * w.x + v.y * w.y + v.z * w.z + v.w * w.w;
  float tot = blk_sum(s, sm);
  if (threadIdx.x == 0) spart[bid] = tot;
}

// ---------------- head final: sum partials per batch ----------------
__global__ void head_final(const float* __restrict__ tpart,
    const float* __restrict__ spart, const float* __restrict__ hb,
    float* __restrict__ out) {
  __shared__ float sm[8];
  int b = blockIdx.x, tid = threadIdx.x;
  float s = 0.f;
  #pragma unroll
  for (int j = 0; j < 4; ++j) s += tpart[b * 1024 + tid * 4 + j];
  s += spart[b * 256 + tid];
  float tot = blk_sum(s, sm);
  if (tid == 0) out[b] = tot * (1.f / 1024.f) + hb[0];
}

// ---------------- depthwise 3x3 + bias + silu (bf16 in/out) ----------------
__global__ __launch_bounds__(256) void dwconv_kernel(const ushort* __restrict__ xc,
    const float* __restrict__ cw, const float* __restrict__ cb, ushort* __restrict__ out) {
  __shared__ float plane[32][33];
  int d = blockIdx.x, b = blockIdx.y;
  long base = ((long)b * 512 + d) * 1024;
  int tid = threadIdx.x;
  uint2 v = *(const uint2*)&xc[base + tid * 4];
  int h0 = (tid * 4) >> 5, w0 = (tid * 4) & 31;
  plane[h0][w0 + 0] = bf2f(v.x & 0xffff); plane[h0][w0 + 1] = bf2f(v.x >> 16);
  plane[h0][w0 + 2] = bf2f(v.y & 0xffff); plane[h0][w0 + 3] = bf2f(v.y >> 16);
  float w9[9];
  #pragma unroll
  for (int i = 0; i < 9; ++i) w9[i] = cw[d * 9 + i];
  float bias = cb[d];
  __syncthreads();
  float o4[4];
  #pragma unroll
  for (int j = 0; j < 4; ++j) {
    int p = tid * 4 + j, h = p >> 5, w = p & 31;
    float acc = 0.f;
    #pragma unroll
    for (int dh = -1; dh <= 1; ++dh) {
      int hy = h + dh;
      if (hy < 0 || hy > 31) continue;
      #pragma unroll
      for (int dw = -1; dw <= 1; ++dw) {
        int wx = w + dw;
        if (wx < 0 || wx > 31) continue;
        acc += w9[(dh + 1) * 3 + (dw + 1)] * plane[hy][wx];
      }
    }
    acc += bias;
    o4[j] = acc / (1.f + __expf(-acc));  // silu
  }
  uint2 o2;
  o2.x = packbf(o4[0], o4[1]);
  o2.y = packbf(o4[2], o4[3]);
  *(uint2*)&out[base + tid * 4] = o2;
}

// --------- build xsT_bf (B,K,L,512) bf16 from xca_bf (B,512,32,32) -----------
__global__ __launch_bounds__(256) void build_xsT(const ushort* __restrict__ xca,
    ushort* __restrict__ xsTb) {
  __shared__ ushort tile[32][34];
  int h = blockIdx.x;
  int d0 = blockIdx.y * 32;
  int z = blockIdx.z;          // z = b*4 + k
  int b = z >> 2, k = z & 3;
  int tid = threadIdx.x;
  int a = tid >> 5, q = tid & 31;
  #pragma unroll
  for (int i = 0; i < 4; ++i) {
    int di = a + i * 8;
    tile[di][q] = xca[((long)(b * 512 + d0 + di)) * 1024 + h * 32 + q];
  }
  __syncthreads();
  #pragma unroll
  for (int i = 0; i < 4; ++i) {
    int w = a + i * 8;
    int r;
    if (k == 0) r = h * 32 + w;
    else if (k == 1) r = w * 32 + h;
    else if (k == 2) r = 1023 - (h * 32 + w);
    else r = 1023 - (w * 32 + h);
    xsTb[((long)z * 1024 + r) * 512 + d0 + q] = tile[q][w];
  }
}

// ------- chunk-parallel selective scan, NC=32, fused dt-projection ----------
template<bool FINAL>
__global__ __launch_bounds__(128) void scan_chunk6(
    const float* __restrict__ xdbl, ushort* xsb,
    const float* __restrict__ dtw, const float* __restrict__ dtb,
    const float* __restrict__ A_log, const float* __restrict__ Ds,
    float* __restrict__ dsum, float* __restrict__ hpb)
{
  __shared__ float sdt[32][64];
  __shared__ float sxv[16][64];
  __shared__ float sy[16][64];        // first 2KB aliased as sR during dt-calc
  __shared__ float sBC[32][32];
  float (*sR)[16] = (float(*)[16])sy;
  int tid = threadIdx.x;
  int dl = tid >> 1, ng = tid & 1;
  int d0 = blockIdx.x * 64;
  int d = d0 + dl;
  int c = blockIdx.y;
  int z = blockIdx.z;
  int k = z & 3;
  long baseD = (long)z * 524288;
  int l0 = c * 32;
  const float* xdz = xdbl + (long)z * 49152 + (long)l0 * 48;
  #pragma unroll
  for (int i = 0; i < 2; ++i) {
    int idx = i * 128 + tid;
    int l = idx >> 3, q = idx & 7;
    *(float4*)&sBC[l][q * 4] = *(const float4*)(xdz + l * 48 + 16 + q * 4);
  }
  {
    int l = tid >> 2, q = tid & 3;
    *(float4*)&sR[l][q * 4] = *(const float4*)(xdz + l * 48 + q * 4);
  }
  float a[8], h[8];
  #pragma unroll
  for (int j = 0; j < 8; ++j) {
    a[j] = -__expf(A_log[((long)k * 512 + d) * 16 + ng * 8 + j]);
    h[j] = 0.f;
  }
  float4 wr0 = *(const float4*)(dtw + ((long)k * 512 + d) * 16);
  float4 wr1 = *(const float4*)(dtw + ((long)k * 512 + d) * 16 + 4);
  float4 wr2 = *(const float4*)(dtw + ((long)k * 512 + d) * 16 + 8);
  float4 wr3 = *(const float4*)(dtw + ((long)k * 512 + d) * 16 + 12);
  float dbias = dtb[k * 512 + d];
  int gbase = c * 65536 + z * 8192 + d * 16 + ng * 8;
  float Dv = 0.f;
  if (FINAL) {
    #pragma unroll
    for (int j = 0; j < 8; ++j) h[j] = hpb[gbase + j];   // h_in (prefix in-place)
    Dv = Ds[k * 512 + d];
  }
  __syncthreads();                 // sR ready
  #pragma unroll
  for (int li = 0; li < 16; ++li) {
    int l = ng * 16 + li;
    const float* rr = &sR[l][0];
    float acc = dbias;
    acc += wr0.x * rr[0];  acc += wr0.y * rr[1];  acc += wr0.z * rr[2];  acc += wr0.w * rr[3];
    acc += wr1.x * rr[4];  acc += wr1.y * rr[5];  acc += wr1.z * rr[6];  acc += wr1.w * rr[7];
    acc += wr2.x * rr[8];  acc += wr2.y * rr[9];  acc += wr2.z * rr[10]; acc += wr2.w * rr[11];
    acc += wr3.x * rr[12]; acc += wr3.y * rr[13]; acc += wr3.z * rr[14]; acc += wr3.w * rr[15];
    sdt[l][dl] = (acc > 20.f) ? acc : __logf(1.f + __expf(acc));
  }
  __syncthreads();                 // sdt ready; sR dead -> sy writable
  int xli = tid >> 3;
  int xdj = (tid & 7) * 8;
  uint4 rxv = *(const uint4*)&xsb[baseD + (long)(l0 + xli) * 512 + d0 + xdj];
  float dtsum = 0.f;
  for (int t = 0; t < 2; ++t) {
    {
      float4 f0, f1;
      f0.x = bf2f(rxv.x & 0xffff); f0.y = bf2f(rxv.x >> 16);
      f0.z = bf2f(rxv.y & 0xffff); f0.w = bf2f(rxv.y >> 16);
      f1.x = bf2f(rxv.z & 0xffff); f1.y = bf2f(rxv.z >> 16);
      f1.z = bf2f(rxv.w & 0xffff); f1.w = bf2f(rxv.w >> 16);
      *(float4*)&sxv[xli][xdj] = f0;
      *(float4*)&sxv[xli][xdj + 4] = f1;
    }
    __syncthreads();
    if (t == 0)
      rxv = *(const uint4*)&xsb[baseD + (long)(l0 + 16 + xli) * 512 + d0 + xdj];
    #pragma unroll
    for (int li = 0; li < 16; ++li) {
      int lr = t * 16 + li;
      float dt = sdt[lr][dl];
      float xv = sxv[li][dl];
      float w = dt * xv;
      float4 B0 = *(const float4*)&sBC[lr][ng * 8];
      float4 B1 = *(const float4*)&sBC[lr][ng * 8 + 4];
      if (!FINAL) {
        dtsum += dt;
        h[0] = __expf(dt * a[0]) * h[0] + w * B0.x;
        h[1] = __expf(dt * a[1]) * h[1] + w * B0.y;
        h[2] = __expf(dt * a[2]) * h[2] + w * B0.z;
        h[3] = __expf(dt * a[3]) * h[3] + w * B0.w;
        h[4] = __expf(dt * a[4]) * h[4] + w * B1.x;
        h[5] = __expf(dt * a[5]) * h[5] + w * B1.y;
        h[6] = __expf(dt * a[6]) * h[6] + w * B1.z;
        h[7] = __expf(dt * a[7]) * h[7] + w * B1.w;
      } else {
        float4 C0 = *(const float4*)&sBC[lr][16 + ng * 8];
        float4 C1 = *(const float4*)&sBC[lr][16 + ng * 8 + 4];
        float p;
        h[0] = __expf(dt * a[0]) * h[0] + w * B0.x; p  = h[0] * C0.x;
        h[1] = __expf(dt * a[1]) * h[1] + w * B0.y; p += h[1] * C0.y;
        h[2] = __expf(dt * a[2]) * h[2] + w * B0.z; p += h[2] * C0.z;
        h[3] = __expf(dt * a[3]) * h[3] + w * B0.w; p += h[3] * C0.w;
        h[4] = __expf(dt * a[4]) * h[4] + w * B1.x; p += h[4] * C1.x;
        h[5] = __expf(dt * a[5]) * h[5] + w * B1.y; p += h[5] * C1.y;
        h[6] = __expf(dt * a[6]) * h[6] + w * B1.z; p += h[6] * C1.z;
        h[7] = __expf(dt * a[7]) * h[7] + w * B1.w; p += h[7] * C1.w;
        p += __shfl_xor(p, 1);
        if (ng == 0) sy[li][dl] = p + Dv * xv;
      }
    }
    __syncthreads();
    if (FINAL) {
      float4 f0 = *(float4*)&sy[xli][xdj];
      float4 f1 = *(float4*)&sy[xli][xdj + 4];
      uint4 o;
      o.x = packbf(f0.x, f0.y); o.y = packbf(f0.z, f0.w);
      o.z = packbf(f1.x, f1.y); o.w = packbf(f1.z, f1.w);
      *(uint4*)&xsb[baseD + (long)(l0 + t * 16 + xli) * 512 + d0 + xdj] = o;
    }
  }
  if (!FINAL) {
    *(float4*)(hpb + gbase)     = make_float4(h[0], h[1], h[2], h[3]);
    *(float4*)(hpb + gbase + 4) = make_float4(h[4], h[5], h[6], h[7]);
    if (ng == 0) dsum[c * 4096 + z * 512 + d] = dtsum;
  }
}

// prefix across the 32 chunks per (z,d,n); recomputes P=exp(dtsum*a);
// writes h_in in-place over hp
__global__ __launch_bounds__(256) void scan_prefix(const float* __restrict__ dsum,
    const float* __restrict__ A_log, float* __restrict__ hpb) {
  int g = blockIdx.x * 256 + threadIdx.x;   // (z,d,n)
  int z = g >> 13, n = g & 15;
  int d = (g >> 4) & 511;
  int k = z & 3;
  float a = -__expf(A_log[((long)k * 512 + d) * 16 + n]);
  float h = 0.f;
  #pragma unroll
  for (int c = 0; c < 32; ++c) {
    float P = __expf(dsum[c * 4096 + z * 512 + d] * a);
    float hp = hpb[c * 65536 + g];
    hpb[c * 65536 + g] = h;
    h = P * h + hp;
  }
}

// -------- fused: combine 4 directions (bf16) + LN over 512 + silu(z) --------
__global__ __launch_bounds__(256) void combine_ln2gate(const ushort* __restrict__ ys,
    const float* __restrict__ zb, ushort* __restrict__ out,
    const float* __restrict__ g, const float* __restrict__ b) {
  __shared__ float sm[8];
  int m = blockIdx.x, tid = threadIdx.x;
  int bb = m >> 10, l = m & 1023;
  int hh = l >> 5, w = l & 31;
  int lw = w * 32 + hh;
  long b4 = (long)bb * 4;
  uint u0 = *(const uint*)&ys[((b4 + 0) * 1024 + l) * 512 + tid * 2];
  uint u1 = *(const uint*)&ys[((b4 + 2) * 1024 + (1023 - l)) * 512 + tid * 2];
  uint u2 = *(const uint*)&ys[((b4 + 1) * 1024 + lw) * 512 + tid * 2];
  uint u3 = *(const uint*)&ys[((b4 + 3) * 1024 + (1023 - lw)) * 512 + tid * 2];
  float v0 = bf2f(u0 & 0xffff) + bf2f(u1 & 0xffff) + bf2f(u2 & 0xffff) + bf2f(u3 & 0xffff);
  float v1 = bf2f(u0 >> 16) + bf2f(u1 >> 16) + bf2f(u2 >> 16) + bf2f(u3 >> 16);
  float s1 = blk_sum(v0 + v1, sm);
  float s2 = blk_sum(v0 * v0 + v1 * v1, sm);
  float mu = s1 * (1.f / 512.f);
  float var = s2 * (1.f / 512.f) - mu * mu;
  float rs = rsqrtf(var + 1e-5f);
  float2 gg = *(const float2*)(g + tid * 2);
  float2 bbv = *(const float2*)(b + tid * 2);
  float2 zz = *(const float2*)(zb + (long)m * 1024 + 0 + tid * 2);
  // NOTE: z layout is [m][512] (C2 buffer), so use 512 stride:
  zz = *(const float2*)(zb + (long)m * 512 + tid * 2);
  float y0 = ((v0 - mu) * rs * gg.x + bbv.x) * (zz.x / (1.f + __expf(-zz.x)));
  float y1 = ((v1 - mu) * rs * gg.y + bbv.y) * (zz.y / (1.f + __expf(-zz.y)));
  *(uint*)&out[(long)m * 512 + tid * 2] = packbf(y0, y1);
}

extern "C" void kernel_launch(void* const* d_in, const int* in_sizes, int n_in,
                              void* d_out, int out_size, void* d_ws, size_t ws_size,
                              hipStream_t stream) {
  const float* x       = (const float*)d_in[0];
  const float* patch_w = (const float*)d_in[1];
  const float* patch_b = (const float*)d_in[2];
  const float* ln_g    = (const float*)d_in[3];
  const float* ln_b    = (const float*)d_in[4];
  const float* in_w    = (const float*)d_in[5];
  const float* conv_w  = (const float*)d_in[6];
  const float* conv_b  = (const float*)d_in[7];
  const float* xproj_w = (const float*)d_in[8];
  const float* dt_w    = (const float*)d_in[9];
  const float* dt_b    = (const float*)d_in[10];
  const float* A_log   = (const float*)d_in[11];
  const float* Ds      = (const float*)d_in[12];
  const float* on_g    = (const float*)d_in[13];
  const float* on_b    = (const float*)d_in[14];
  const float* out_w   = (const float*)d_in[15];
  const float* head_w  = (const float*)d_in[16];
  const float* head_b  = (const float*)d_in[17];

  float* ws = (float*)d_ws;
  float* t_buf   = ws;                    // tpart(2048) + spart(512)
  float* u_buf   = t_buf + 524288;        // u_bf16 overlay
  float* xz_buf  = u_buf + 524288;        // pw_hi overlay; later z_buf
  float* xc_buf  = xz_buf + 2097152;      // xc_bf overlay
  float* xca_buf = xc_buf + 1048576;      // xca_bf overlay; later y_bf
  float* xsT_buf = xca_buf + 1048576;     // A_p overlay
  float* xdbl_buf= xsT_buf + 4194304;     // 8*1024*48
  float* spl_buf = xdbl_buf + 393216;     // P_patch / P_out overlay
  float* tail    = spl_buf + 4194304;
  // overlays:
  float*  tpart  = t_buf;                           // 2048 f
  float*  spart  = t_buf + 2048;                    // 512 f
  ushort* A_p    = (ushort*)xsT_buf;                // 2048*4096 us
  ushort* pw_hi  = (ushort*)xz_buf;                 // 1048576 us
  float*  z_buf  = xz_buf;                          // 2048*512 f (after patch mfma)
  float*  P_patch= spl_buf;                         // 8*524288 f
  float*  P_out  = spl_buf;                         // 4*524288 f
  ushort* u_bf   = (ushort*)u_buf;
  ushort* xc_bf  = (ushort*)xc_buf;
  ushort* xca_bf = (ushort*)xca_buf;
  ushort* y_bf   = (ushort*)xca_buf;                // after build_xsT
  // tail: weight splits, xsT bf16, scan dtsum/hp
  ushort* iw_hi  = (ushort*)tail;                   // 262144 us
  ushort* iw_lo  = (ushort*)(tail + 131072);
  ushort* ow_hi  = (ushort*)(tail + 262144);        // 131072 us
  ushort* ow_lo  = (ushort*)(tail + 327680);
  ushort* xw_hi  = (ushort*)(tail + 393216);        // 98304 us
  ushort* xw_lo  = (ushort*)(tail + 442368);
  ushort* xsT_bf = (ushort*)(tail + 491520);        // 4194304 us
  float*  dsum_buf = tail + 2588672;                // 131072 f
  float*  hp_buf   = tail + 2719744;                // 2097152 f

  // 0. fused prep: im2col A + weight splits (patch hi-only)
  prep_kernel<<<8065, 256, 0, stream>>>(x, A_p, patch_w, in_w, out_w, xproj_w,
      pw_hi, iw_hi, iw_lo, ow_hi, ow_lo, xw_hi, xw_lo);
  // 1. patch embed MFMA (hi-only), split-K=8 -> partials
  mfma_bf<<<512, 512, 0, stream>>>(A_p, pw_hi, nullptr, P_patch, nullptr,
      2048, 256, 4096, 512, 0, 16, 8, 0);
  // 2. fused reduce + bias + LN1 -> u (bf16); tpart head partial
  reduce_ln1<<<2048, 256, 0, stream>>>(P_patch, patch_b, ln_g, ln_b, u_bf,
      head_w, tpart);
  // 3. in-proj MFMA fused epilogue: xc (transposed bf16) + z (f32)
  mfma_bf<<<256, 512, 0, stream>>>(u_bf, iw_hi, iw_lo, xc_buf, z_buf,
      2048, 1024, 256, 256, 2, 16, 1, 1);
  // 4. depthwise conv + silu -> xca (bf16)
  dwconv_kernel<<<dim3(512, 2), 256, 0, stream>>>(xc_bf, conv_w, conv_b, xca_bf);
  // 5. build xsT (bf16, 4 directions)
  build_xsT<<<dim3(32, 16, 8), 256, 0, stream>>>(xca_bf, xsT_bf);
  // 6. x_dbl[z] (1024,48) = xsT_bf[z] @ xproj[k]^T (MFMA)
  mfma_x<<<dim3(16, 8), 256, 0, stream>>>(xsT_bf, xw_hi, xw_lo, xdbl_buf);
  // 7. chunk-parallel selective scan (NC=32, fused dt-projection)
  scan_chunk6<false><<<dim3(8, 32, 8), 128, 0, stream>>>(xdbl_buf, xsT_bf,
      dt_w, dt_b, A_log, Ds, dsum_buf, hp_buf);
  scan_prefix<<<256, 256, 0, stream>>>(dsum_buf, A_log, hp_buf);
  scan_chunk6<true><<<dim3(8, 32, 8), 128, 0, stream>>>(xdbl_buf, xsT_bf,
      dt_w, dt_b, A_log, Ds, dsum_buf, hp_buf);
  // 8. fused combine + LN2 + silu gate -> y_bf16
  combine_ln2gate<<<2048, 256, 0, stream>>>(xsT_bf, z_buf, y_bf, on_g, on_b);
  // 9. ss = y @ out_w^T (MFMA split-K=4) -> partials; head dot fused in reduce
  mfma_bf<<<256, 512, 0, stream>>>(y_bf, ow_hi, ow_lo, P_out, nullptr,
      2048, 256, 512, 128, 0, 16, 4, 1);
  reduce_ss<<<512, 256, 0, stream>>>(P_out, head_w, spart);
  // 10. head final
  head_final<<<2, 256, 0, stream>>>(tpart, spart, head_b, (float*)d_out);
}